// Round 12
// baseline (415.982 us; speedup 1.0000x reference)
//
#include <hip/hip_runtime.h>
#include <math.h>

typedef __attribute__((ext_vector_type(8))) short bf16x8;
typedef __attribute__((ext_vector_type(4))) float f32x4;

__device__ __forceinline__ float bfbits2f(unsigned short b){
  return __uint_as_float(((unsigned)b) << 16);
}
__device__ __forceinline__ unsigned short f2bfbits(float f){
  unsigned u = __float_as_uint(f);
  unsigned r = u + 0x7fffu + ((u >> 16) & 1u);
  return (unsigned short)(r >> 16);
}

// ================= Threefry-2x32 (JAX partitionable) =================
__host__ __device__ __forceinline__ unsigned rotl32(unsigned v, int d){
  return (v << d) | (v >> (32 - d));
}
__host__ __device__ __forceinline__ void tf2x32(unsigned k0, unsigned k1,
                                                unsigned c0, unsigned c1,
                                                unsigned &o0, unsigned &o1)
{
  unsigned ks2 = k0 ^ k1 ^ 0x1BD11BDAu;
  unsigned x0 = c0 + k0, x1 = c1 + k1;
#define TFR(r) x0 += x1; x1 = rotl32(x1, r); x1 ^= x0;
  TFR(13) TFR(15) TFR(26) TFR(6)
  x0 += k1;  x1 += ks2 + 1u;
  TFR(17) TFR(29) TFR(16) TFR(24)
  x0 += ks2; x1 += k0 + 2u;
  TFR(13) TFR(15) TFR(26) TFR(6)
  x0 += k0;  x1 += k1 + 3u;
  TFR(17) TFR(29) TFR(16) TFR(24)
  x0 += k1;  x1 += ks2 + 4u;
  TFR(13) TFR(15) TFR(26) TFR(6)
  x0 += ks2; x1 += k0 + 5u;
#undef TFR
  o0 = x0; o1 = x1;
}

// ================= CSR build (2 edges/thread for concurrency) =================
__global__ __launch_bounds__(256) void k_countpos(const int* __restrict__ dst,
                                                  int* __restrict__ cnt,
                                                  int* __restrict__ pos, int E)
{
  int g = blockIdx.x * 256 + threadIdx.x;
  int base = g * 2;
  if (base + 1 < E){
    int2 d = ((const int2*)dst)[g];
    int2 p;
    p.x = atomicAdd(&cnt[d.x], 1);
    p.y = atomicAdd(&cnt[d.y], 1);
    ((int2*)pos)[g] = p;
  } else if (base < E){
    pos[base] = atomicAdd(&cnt[dst[base]], 1);
  }
}

__global__ __launch_bounds__(256) void k_blocksum(const int* __restrict__ cnt,
                                                  int* __restrict__ bsum, int N)
{
  __shared__ int sh[256];
  int t = threadIdx.x;
  int base = blockIdx.x * 1024 + t * 4;
  int s = 0;
  #pragma unroll
  for (int j = 0; j < 4; j++){ int i = base + j; if (i < N) s += cnt[i]; }
  sh[t] = s; __syncthreads();
  for (int off = 128; off; off >>= 1){
    if (t < off) sh[t] += sh[t + off];
    __syncthreads();
  }
  if (t == 0) bsum[blockIdx.x] = sh[0];
}

__global__ __launch_bounds__(256) void k_scansums(const int* __restrict__ bsum,
                                                  int* __restrict__ boff,
                                                  int* __restrict__ rowstart,
                                                  int NB, int N)
{
  __shared__ int sh[256];
  int t = threadIdx.x;
  int v = (t < NB) ? bsum[t] : 0;
  sh[t] = v; __syncthreads();
  for (int off = 1; off < 256; off <<= 1){
    int x = sh[t];
    int y = (t >= off) ? sh[t - off] : 0;
    __syncthreads();
    sh[t] = x + y;
    __syncthreads();
  }
  if (t < NB) boff[t] = sh[t] - v;
  if (t == NB - 1) rowstart[N] = sh[t];
}

__global__ __launch_bounds__(256) void k_scanfinal(const int* __restrict__ cnt,
                                                   const int* __restrict__ boff,
                                                   int* __restrict__ rowstart,
                                                   float* __restrict__ dinv, int N)
{
  __shared__ int sh[256];
  int t = threadIdx.x;
  int base = blockIdx.x * 1024 + t * 4;
  int c0 = 0, c1 = 0, c2 = 0, c3 = 0;
  if (base + 0 < N) c0 = cnt[base + 0];
  if (base + 1 < N) c1 = cnt[base + 1];
  if (base + 2 < N) c2 = cnt[base + 2];
  if (base + 3 < N) c3 = cnt[base + 3];
  int s = c0 + c1 + c2 + c3;
  sh[t] = s; __syncthreads();
  for (int off = 1; off < 256; off <<= 1){
    int x = sh[t];
    int y = (t >= off) ? sh[t - off] : 0;
    __syncthreads();
    sh[t] = x + y;
    __syncthreads();
  }
  int excl = sh[t] - s + boff[blockIdx.x];
  if (base + 0 < N){ rowstart[base+0] = excl;          dinv[base+0] = rsqrtf((float)c0 + 1.f); }
  if (base + 1 < N){ rowstart[base+1] = excl+c0;       dinv[base+1] = rsqrtf((float)c1 + 1.f); }
  if (base + 2 < N){ rowstart[base+2] = excl+c0+c1;    dinv[base+2] = rsqrtf((float)c2 + 1.f); }
  if (base + 3 < N){ rowstart[base+3] = excl+c0+c1+c2; dinv[base+3] = rsqrtf((float)c3 + 1.f); }
}

__global__ __launch_bounds__(256) void k_fill(const int* __restrict__ src,
                                              const int* __restrict__ dst,
                                              const int* __restrict__ pos,
                                              const int* __restrict__ rowstart,
                                              int* __restrict__ csr, int E)
{
  int g = blockIdx.x * 256 + threadIdx.x;
  int base = g * 2;
  if (base + 1 < E){
    int2 d = ((const int2*)dst)[g];
    int2 p = ((const int2*)pos)[g];
    int2 s = ((const int2*)src)[g];
    int r0 = rowstart[d.x], r1 = rowstart[d.y];
    csr[r0 + p.x] = s.x;
    csr[r1 + p.y] = s.y;
  } else if (base < E){
    csr[rowstart[dst[base]] + pos[base]] = src[base];
  }
}

// ====== weight transpose: WT[n][k] bf16, row stride 128 (unpadded) ======
__global__ __launch_bounds__(256) void k_wt(const float* __restrict__ W1,
                                            const float* __restrict__ W2,
                                            const float* __restrict__ W3,
                                            unsigned short* __restrict__ WT1,
                                            unsigned short* __restrict__ WT2,
                                            unsigned short* __restrict__ WT3)
{
  const float* W; unsigned short* WT; int Cout, Cpad;
  if (blockIdx.x == 0){ W = W1; WT = WT1; Cout = 128; Cpad = 128; }
  else if (blockIdx.x == 1){ W = W2; WT = WT2; Cout = 128; Cpad = 128; }
  else { W = W3; WT = WT3; Cout = 40; Cpad = 48; }
  int tot = Cpad * 128;
  for (int i = threadIdx.x; i < tot; i += 256){
    int n = i >> 7, k = i & 127;
    float v = (n < Cout) ? W[k * Cout + n] : 0.f;
    WT[i] = f2bfbits(v);
  }
}

// ================= MFMA GEMM: wave-private A staging + precomputed drop mask ======
// MODE 0: A fp32 raw (layer 1). MODE 2: A bf16 + BN/ReLU + mask-based dropout.
template<int NT, int MODE>
__global__ __launch_bounds__(256) void k_gemm_mfma(const void* __restrict__ Ap,
                                                   const unsigned short* __restrict__ WT,
                                                   const float* __restrict__ dinv,
                                                   const float* __restrict__ stats,
                                                   const float* __restrict__ g,
                                                   const float* __restrict__ be,
                                                   const unsigned* __restrict__ mask,
                                                   float invN,
                                                   unsigned short* __restrict__ outb,
                                                   int N, int Cout)
{
  __shared__ uint4 Wl4[NT * 16 * 16];          // NT*16 rows x 16 chunks, swizzled
  __shared__ uint4 Al4[64 * 16];               // 64 rows x 16 chunks, swizzled
  __shared__ float bnS[128], bnB[128];
  const int t = threadIdx.x;
  const int w = t >> 6, l = t & 63;
  const long rb0 = (long)blockIdx.x * 64;
  const int wrow0 = w * 16;

  // ---- issue raw A (+mask) loads first (latency hidden behind W/bn stage) ----
  uint4 rawU[4];
  float4 rawF[4][2];
  unsigned mword[4];
  int rr[4], cc[4];
  bool inr[4];
  #pragma unroll
  for (int i = 0; i < 4; i++){
    int idx = i * 64 + l;
    int r = idx >> 4, c = idx & 15;
    long grow = rb0 + wrow0 + r;
    rr[i] = r; cc[i] = c; inr[i] = (grow < N);
    if (inr[i]){
      if (MODE == 0){
        const float* ap = (const float*)Ap + grow * 128 + c * 8;
        rawF[i][0] = *(const float4*)ap;
        rawF[i][1] = *(const float4*)(ap + 4);
      } else {
        rawU[i] = *(const uint4*)((const unsigned short*)Ap + grow * 128 + c * 8);
        mword[i] = mask[((unsigned)grow << 2) + (c >> 2)];
      }
    }
  }

  // ---- shared W stage (+ BN prep), single block barrier ----
  {
    const uint4* s4 = (const uint4*)WT;
    const int tot = NT * 16 * 16;
    for (int i = t; i < tot; i += 256){
      int n = i >> 4, c = i & 15;
      Wl4[n * 16 + (c ^ (n & 15))] = s4[i];
    }
  }
  if (MODE == 2 && t < 128){
    float ss = 0.f, qq = 0.f;
    #pragma unroll
    for (int i = 0; i < 16; i++){
      ss += stats[i * 256 + t];
      qq += stats[i * 256 + 128 + t];
    }
    float mean = ss * invN;
    float var = fmaxf(qq * invN - mean * mean, 0.f);
    float rstd = rsqrtf(var + 1e-5f);
    float sc = g[t] * rstd;
    bnS[t] = sc;
    bnB[t] = be[t] - mean * sc;
  }
  __syncthreads();

  // ---- transform + wave-private LDS write (no block barrier needed) ----
  #pragma unroll
  for (int i = 0; i < 4; i++){
    uint4 chunk = make_uint4(0u, 0u, 0u, 0u);
    if (inr[i]){
      if (MODE == 0){
        chunk.x = (unsigned)f2bfbits(rawF[i][0].x) | ((unsigned)f2bfbits(rawF[i][0].y) << 16);
        chunk.y = (unsigned)f2bfbits(rawF[i][0].z) | ((unsigned)f2bfbits(rawF[i][0].w) << 16);
        chunk.z = (unsigned)f2bfbits(rawF[i][1].x) | ((unsigned)f2bfbits(rawF[i][1].y) << 16);
        chunk.w = (unsigned)f2bfbits(rawF[i][1].z) | ((unsigned)f2bfbits(rawF[i][1].w) << 16);
      } else {
        unsigned mb = mword[i] >> ((cc[i] & 3) * 8);   // 8 drop bits for this chunk
        const unsigned* rw = &rawU[i].x;
        unsigned* cw = &chunk.x;
        #pragma unroll
        for (int h = 0; h < 4; h++){
          int ch = cc[i] * 8 + 2 * h;
          float f0 = bfbits2f((unsigned short)(rw[h] & 0xffffu));
          float f1 = bfbits2f((unsigned short)(rw[h] >> 16));
          f0 = fmaxf(fmaf(f0, bnS[ch],     bnB[ch]),     0.f);
          f1 = fmaxf(fmaf(f1, bnS[ch + 1], bnB[ch + 1]), 0.f);
          f0 = ((mb >> (2 * h))     & 1u) ? 0.f : f0 * 2.f;
          f1 = ((mb >> (2 * h + 1)) & 1u) ? 0.f : f1 * 2.f;
          cw[h] = (unsigned)f2bfbits(f0) | ((unsigned)f2bfbits(f1) << 16);
        }
      }
    }
    Al4[(wrow0 + rr[i]) * 16 + (cc[i] ^ rr[i])] = chunk;
  }

  const int lm = l & 15, q = l >> 4;

  f32x4 acc[NT];
  #pragma unroll
  for (int nt = 0; nt < NT; nt++){
    acc[nt][0] = 0.f; acc[nt][1] = 0.f; acc[nt][2] = 0.f; acc[nt][3] = 0.f;
  }

  #pragma unroll
  for (int kt = 0; kt < 4; kt++){
    const int x = kt * 4 + q;
    bf16x8 a = *(const bf16x8*)&Al4[(wrow0 + lm) * 16 + (x ^ lm)];
    #pragma unroll
    for (int nt = 0; nt < NT; nt++){
      int brow = nt * 16 + lm;
      bf16x8 b = *(const bf16x8*)&Wl4[brow * 16 + (x ^ (brow & 15))];
      acc[nt] = __builtin_amdgcn_mfma_f32_16x16x32_bf16(a, b, acc[nt], 0, 0, 0);
    }
  }

  #pragma unroll
  for (int r = 0; r < 4; r++){
    long row = rb0 + wrow0 + q * 4 + r;
    if (row < N){
      float dv = dinv[row];
      #pragma unroll
      for (int nt = 0; nt < NT; nt++){
        int col = nt * 16 + lm;
        if (col < Cout)
          outb[row * Cout + col] = f2bfbits(acc[nt][r] * dv);
      }
    }
  }
}

// ====== aggregation (128 ch) + fused BN stats + INTERLEAVED mask generation ======
// Each thread owns 16 mask bits (one ushort); 4-hash batches are issued inside
// the gather loop so hash VALU fills the vmcnt shadow of outstanding gathers.
#define ACC8(U) do{ uint4 _u = (U); \
  a0 += bfbits2f((unsigned short)(_u.x & 0xffffu)); \
  a1 += bfbits2f((unsigned short)(_u.x >> 16)); \
  a2 += bfbits2f((unsigned short)(_u.y & 0xffffu)); \
  a3 += bfbits2f((unsigned short)(_u.y >> 16)); \
  a4 += bfbits2f((unsigned short)(_u.z & 0xffffu)); \
  a5 += bfbits2f((unsigned short)(_u.z >> 16)); \
  a6 += bfbits2f((unsigned short)(_u.w & 0xffffu)); \
  a7 += bfbits2f((unsigned short)(_u.w >> 16)); }while(0)

#define HASH4 do{ if (jm < 16){ \
  _Pragma("unroll") \
  for (int jj = 0; jj < 4; jj++){ \
    unsigned h0, h1; \
    tf2x32(mk0, mk1, 0u, cbase + (unsigned)(jm + jj), h0, h1); \
    mbits |= (((h0 ^ h1) >> 31) << (jm + jj)); \
  } jm += 4; } }while(0)

__global__ __launch_bounds__(256) void k_agg128s(const unsigned short* __restrict__ hw,
                                                 const int* __restrict__ rs,
                                                 const int* __restrict__ csr,
                                                 const float* __restrict__ dinv,
                                                 unsigned short* __restrict__ outb,
                                                 float* __restrict__ stats,
                                                 unsigned short* __restrict__ mask16,
                                                 unsigned mk0, unsigned mk1, int N8,
                                                 int N)
{
  const int l = threadIdx.x;
  const int ns = l >> 4;                 // node-sub 0..3
  const int sl = l & 15;                 // sublane 0..15
  const int ty = threadIdx.y;
  const int grp = ty * 4 + ns;           // 0..15 chain id
  const uint4* h16 = (const uint4*)hw;   // row = 16 uint4 (256 B)
  const int base = blockIdx.x * 32;

  const int si = blockIdx.x * 256 + ty * 64 + l;   // ushort index
  const unsigned cbase = (unsigned)si * 16u;
  unsigned mbits = 0u;
  int jm = 0;

  float s0=0.f,s1=0.f,s2=0.f,s3=0.f,s4=0.f,s5=0.f,s6=0.f,s7=0.f;
  float q0=0.f,q1=0.f,q2=0.f,q3=0.f,q4=0.f,q5=0.f,q6=0.f,q7=0.f;

  #pragma unroll 1
  for (int it = 0; it < 2; it++){
    int v = base + it * 16 + grp;
    if (v < N){
      float a0=0.f,a1=0.f,a2=0.f,a3=0.f,a4=0.f,a5=0.f,a6=0.f,a7=0.f;
      ACC8(h16[(size_t)v * 16 + sl]);
      int e0 = rs[v], e1 = rs[v + 1];
      int i = e0;
      for (; i + 4 <= e1; i += 4){
        int sa = csr[i], sb = csr[i+1], sc = csr[i+2], sd = csr[i+3];
        uint4 m0 = h16[(size_t)sa * 16 + sl];
        uint4 m1 = h16[(size_t)sb * 16 + sl];
        uint4 m2 = h16[(size_t)sc * 16 + sl];
        uint4 m3 = h16[(size_t)sd * 16 + sl];
        HASH4;                            // hash work inside the vmcnt shadow
        ACC8(m0); ACC8(m1); ACC8(m2); ACC8(m3);
      }
      for (; i < e1; i++){
        uint4 m0 = h16[(size_t)csr[i] * 16 + sl];
        HASH4;
        ACC8(m0);
      }
      float dv = dinv[v];
      a0*=dv; a1*=dv; a2*=dv; a3*=dv; a4*=dv; a5*=dv; a6*=dv; a7*=dv;
      uint4 o;
      o.x = (unsigned)f2bfbits(a0) | ((unsigned)f2bfbits(a1) << 16);
      o.y = (unsigned)f2bfbits(a2) | ((unsigned)f2bfbits(a3) << 16);
      o.z = (unsigned)f2bfbits(a4) | ((unsigned)f2bfbits(a5) << 16);
      o.w = (unsigned)f2bfbits(a6) | ((unsigned)f2bfbits(a7) << 16);
      ((uint4*)outb)[(size_t)v * 16 + sl] = o;
      s0+=a0; q0=fmaf(a0,a0,q0);  s1+=a1; q1=fmaf(a1,a1,q1);
      s2+=a2; q2=fmaf(a2,a2,q2);  s3+=a3; q3=fmaf(a3,a3,q3);
      s4+=a4; q4=fmaf(a4,a4,q4);  s5+=a5; q5=fmaf(a5,a5,q5);
      s6+=a6; q6=fmaf(a6,a6,q6);  s7+=a7; q7=fmaf(a7,a7,q7);
    }
  }

  // finish remaining hashes (short tail) and store this thread's 16 bits
  while (jm < 16){ HASH4; }
  if (si < N8) mask16[si] = (unsigned short)mbits;

  __shared__ float shS[16][128], shQ[16][128];
  *(float4*)&shS[grp][sl * 8]     = make_float4(s0, s1, s2, s3);
  *(float4*)&shS[grp][sl * 8 + 4] = make_float4(s4, s5, s6, s7);
  *(float4*)&shQ[grp][sl * 8]     = make_float4(q0, q1, q2, q3);
  *(float4*)&shQ[grp][sl * 8 + 4] = make_float4(q4, q5, q6, q7);
  __syncthreads();
  int t = ty * 64 + threadIdx.x;
  if (t < 128){
    float ss = 0.f, qq = 0.f;
    #pragma unroll
    for (int g2 = 0; g2 < 16; g2++){ ss += shS[g2][t]; qq += shQ[g2][t]; }
    float* dstat = stats + (blockIdx.x & 15) * 256;
    atomicAdd(&dstat[t], ss);
    atomicAdd(&dstat[128 + t], qq);
  }
}

// ============ layer-3 agg (40 ch) + bias + log_softmax ============
// 4 nodes/wave: node = 16-lane group, lanes 0..9 hold uint2 (4 ch each).
__global__ __launch_bounds__(256) void k_agg40lsm(const unsigned short* __restrict__ hw,
                                                  const int* __restrict__ rs,
                                                  const int* __restrict__ csr,
                                                  const float* __restrict__ dinv,
                                                  const float* __restrict__ b3,
                                                  float* __restrict__ out, int N)
{
  const int l = threadIdx.x;
  const int ns = l >> 4, sl = l & 15;
  const int v = blockIdx.x * 16 + threadIdx.y * 4 + ns;
  const bool act = (v < N) && (sl < 10);
  const uint2* h2 = (const uint2*)hw;              // row = 10 uint2 (80 B)
  float a0 = 0.f, a1 = 0.f, a2 = 0.f, a3 = 0.f, dv = 1.f;
  if (act){
    dv = dinv[v];
    uint2 u = h2[(size_t)v * 10 + sl];
    a0 = bfbits2f((unsigned short)(u.x & 0xffffu));
    a1 = bfbits2f((unsigned short)(u.x >> 16));
    a2 = bfbits2f((unsigned short)(u.y & 0xffffu));
    a3 = bfbits2f((unsigned short)(u.y >> 16));
    int e0 = rs[v], e1 = rs[v + 1];
    int i = e0;
#define ACCU2(U) do{ uint2 _u = (U); \
    a0 += bfbits2f((unsigned short)(_u.x & 0xffffu)); \
    a1 += bfbits2f((unsigned short)(_u.x >> 16)); \
    a2 += bfbits2f((unsigned short)(_u.y & 0xffffu)); \
    a3 += bfbits2f((unsigned short)(_u.y >> 16)); }while(0)
    for (; i + 4 <= e1; i += 4){
      int sa = csr[i], sb = csr[i+1], sc = csr[i+2], sd = csr[i+3];
      uint2 m0 = h2[(size_t)sa * 10 + sl];
      uint2 m1 = h2[(size_t)sb * 10 + sl];
      uint2 m2 = h2[(size_t)sc * 10 + sl];
      uint2 m3 = h2[(size_t)sd * 10 + sl];
      ACCU2(m0); ACCU2(m1); ACCU2(m2); ACCU2(m3);
    }
    for (; i < e1; i++){
      ACCU2(h2[(size_t)csr[i] * 10 + sl]);
    }
#undef ACCU2
  }
  float x0 = act ? fmaf(a0, dv, b3[sl * 4 + 0]) : -INFINITY;
  float x1 = act ? fmaf(a1, dv, b3[sl * 4 + 1]) : -INFINITY;
  float x2 = act ? fmaf(a2, dv, b3[sl * 4 + 2]) : -INFINITY;
  float x3 = act ? fmaf(a3, dv, b3[sl * 4 + 3]) : -INFINITY;
  float m = fmaxf(fmaxf(x0, x1), fmaxf(x2, x3));
  #pragma unroll
  for (int off = 8; off; off >>= 1) m = fmaxf(m, __shfl_xor(m, off, 16));
  float e = act ? (expf(x0 - m) + expf(x1 - m) + expf(x2 - m) + expf(x3 - m)) : 0.f;
  #pragma unroll
  for (int off = 8; off; off >>= 1) e += __shfl_xor(e, off, 16);
  float lse = m + logf(e);
  if (act){
    float4 o;
    o.x = x0 - lse; o.y = x1 - lse; o.z = x2 - lse; o.w = x3 - lse;
    *reinterpret_cast<float4*>(out + (size_t)v * 40 + sl * 4) = o;
  }
}

// ================= launch =================
extern "C" void kernel_launch(void* const* d_in, const int* in_sizes, int n_in,
                              void* d_out, int out_size, void* d_ws, size_t ws_size,
                              hipStream_t stream)
{
  const float* x  = (const float*)d_in[0];
  const int* ei   = (const int*)d_in[1];
  const float* W1 = (const float*)d_in[2];
  const float* g1 = (const float*)d_in[4];
  const float* be1= (const float*)d_in[5];
  const float* W2 = (const float*)d_in[6];
  const float* g2 = (const float*)d_in[8];
  const float* be2= (const float*)d_in[9];
  const float* W3 = (const float*)d_in[10];
  const float* b3 = (const float*)d_in[11];
  float* out = (float*)d_out;
  // b1, b2 unused: per-channel constants cancel exactly in training-mode BN.

  const int N = in_sizes[0] / 128;
  const int E = in_sizes[1] / 2;
  const int* srcv = ei;
  const int* dstv = ei + E;

  char* ws = (char*)d_ws;
  size_t off = 0;
  auto take = [&](size_t bytes) -> void* {
    void* p = ws + off;
    off = (off + bytes + 255) & ~(size_t)255;
    return p;
  };
  int*   cnt      = (int*)  take((size_t)N * 4);
  int*   pos      = (int*)  take((size_t)E * 4);
  int*   rowstart = (int*)  take((size_t)(N + 1) * 4);
  int*   csr      = (int*)  take((size_t)E * 4);
  float* dinv     = (float*)take((size_t)N * 4);
  int*   bsum     = (int*)  take(256 * 4);
  int*   boff     = (int*)  take(256 * 4);
  float* stats1   = (float*)take(2 * 16 * 256 * 4);    // two banked stat sets
  float* stats2   = stats1 + 16 * 256;
  unsigned* mask1 = (unsigned*)take((size_t)N * 4 * 4);  // N*128 bits
  unsigned* mask2 = (unsigned*)take((size_t)N * 4 * 4);
  unsigned short* WT1 = (unsigned short*)take(128 * 128 * 2);
  unsigned short* WT2 = (unsigned short*)take(128 * 128 * 2);
  unsigned short* WT3 = (unsigned short*)take(48 * 128 * 2);
  unsigned short* bufX = (unsigned short*)take((size_t)N * 128 * 2);
  unsigned short* bufY = (unsigned short*)take((size_t)N * 128 * 2);
  (void)ws_size; (void)n_in; (void)out_size;

  // dropout subkeys: jax.random.split(key(42), 2), partitionable fold
  unsigned l1k0, l1k1, l2k0, l2k1;
  tf2x32(0u, 42u, 0u, 0u, l1k0, l1k1);
  tf2x32(0u, 42u, 0u, 1u, l2k0, l2k1);

  const float invN = 1.0f / (float)N;
  const int N8 = N * 8;                 // mask ushorts (N*128/16)
  const int NB = (N + 1023) / 1024;
  dim3 wblk(64, 4);
  dim3 wgrid16((N + 15) / 16);
  dim3 wgrid32((N + 31) / 32);
  const int ggrid = (N + 63) / 64;
  const int egrid2 = (E + 511) / 512;

  // ---- graph structure ----
  hipMemsetAsync(cnt, 0, (size_t)N * 4, stream);
  hipMemsetAsync(stats1, 0, 2 * 16 * 256 * 4, stream);
  k_countpos<<<egrid2, 256, 0, stream>>>(dstv, cnt, pos, E);
  k_blocksum<<<NB, 256, 0, stream>>>(cnt, bsum, N);
  k_scansums<<<1, 256, 0, stream>>>(bsum, boff, rowstart, NB, N);
  k_scanfinal<<<NB, 256, 0, stream>>>(cnt, boff, rowstart, dinv, N);
  k_fill<<<egrid2, 256, 0, stream>>>(srcv, dstv, pos, rowstart, csr, E);
  k_wt<<<3, 256, 0, stream>>>(W1, W2, W3, WT1, WT2, WT3);

  // ---- layer 1 ----
  k_gemm_mfma<8, 0><<<ggrid, 256, 0, stream>>>(x, WT1, dinv,
      nullptr, nullptr, nullptr, nullptr, invN, bufX, N, 128);
  k_agg128s<<<wgrid32, wblk, 0, stream>>>(bufX, rowstart, csr, dinv, bufY, stats1,
      (unsigned short*)mask1, l1k0, l1k1, N8, N);

  // ---- layer 2 (BN1+ReLU+dropout-mask fused into A staging) ----
  k_gemm_mfma<8, 2><<<ggrid, 256, 0, stream>>>(bufY, WT2, dinv,
      stats1, g1, be1, mask1, invN, bufX, N, 128);
  k_agg128s<<<wgrid32, wblk, 0, stream>>>(bufX, rowstart, csr, dinv, bufY, stats2,
      (unsigned short*)mask2, l2k0, l2k1, N8, N);

  // ---- layer 3 (BN2+ReLU+dropout-mask fused) + log_softmax ----
  k_gemm_mfma<3, 2><<<ggrid, 256, 0, stream>>>(bufY, WT3, dinv,
      stats2, g2, be2, mask2, invN, bufX, N, 40);
  k_agg40lsm<<<wgrid16, wblk, 0, stream>>>(bufX, rowstart, csr, dinv, b3, out, N);
}